// Round 5
// baseline (521.225 us; speedup 1.0000x reference)
//
#include <hip/hip_runtime.h>
#include <hip/hip_bf16.h>
#include <cstdint>

// Static problem sizes
#define BB 32
#define CC 512
#define NSQ 4096      // N*N
#define SS 128
#define MM 256
#define NTILE 32      // 4096/128 position-tiles per video
#define NBIG (BB*NTILE)   // 1024 big blocks

// ws layout (byte offsets)
#define WS_SN   0         // sents_norm fp32: 128*512*4 = 262144
#define WS_SNB  262144    // sents_norm bf16: 128*512*2 = 131072
#define WS_IV   393216    // iv_all: 256*128*4 = 131072
#define WS_PART 524288    // negq partials: 1024*128*4 = 524288

typedef short bf16x8 __attribute__((ext_vector_type(8)));   // 8 bf16 raw (4 VGPRs)
typedef float f32x4  __attribute__((ext_vector_type(4)));   // MFMA accumulator

__device__ __forceinline__ unsigned short f2bf(float x) {
    unsigned int u = __float_as_uint(x);
    unsigned int r = (u + 0x7fffu + ((u >> 16) & 1u)) >> 16;   // RNE
    return (unsigned short)r;
}

__device__ __forceinline__ unsigned pk2(float a, float b) {   // v_cvt_pk_bf16_f32
    union { __hip_bfloat162 h; unsigned u; } cv;
    cv.h = __float22bfloat162_rn(make_float2(a, b));
    return cv.u;
}

// ---------------------------------------------------------------------------
// prep: 128 blocks normalize sents rows (fp32 + bf16 copies).
__global__ void k_prep(const float* __restrict__ sents, float* __restrict__ sn,
                       unsigned short* __restrict__ snb) {
    const int blk = blockIdx.x, t = threadIdx.x;
    __shared__ float red[256];
    const float* row = sents + (size_t)blk * CC;
    float x0 = row[t], x1 = row[t + 256];
    red[t] = x0 * x0 + x1 * x1;
    __syncthreads();
    for (int off = 128; off > 0; off >>= 1) {
        if (t < off) red[t] += red[t + off];
        __syncthreads();
    }
    float rn = 1.0f / fmaxf(sqrtf(red[0]), 1e-12f);
    float y0 = x0 * rn, y1 = x1 * rn;
    sn[(size_t)blk * CC + t]        = y0;
    sn[(size_t)blk * CC + t + 256]  = y1;
    snb[(size_t)blk * CC + t]       = f2bf(y0);
    snb[(size_t)blk * CC + t + 256] = f2bf(y1);
}

// ---------------------------------------------------------------------------
// Mega kernel. Blocks 0..255: per-target path. Blocks 256..1279: dense
// 128(sent) x 128(pos) MFMA score tile of video b = (bid>>5),
// positions pos0..pos0+127 (bid&31)*128. Invalid (lower-tri) columns are
// masked to 0 in the epilogue.
//
// LDS swizzle: element (row,k) of a 128x64 bf16 tile at
//   row*64 + ((G ^ (row&7) ^ ((row>>3)&7))&7)*8 + (k&7),  G = k>>3.
// Bank-enumeration: staging ds_write_b128 and frag ds_read_b128 both spread
// 8 accesses/bank (conflict-free).

union SMem {
    struct {
        unsigned short sA[128 * 64];   // 16 KB sents tile
        unsigned short vB[128 * 64];   // 16 KB video tile
        float sqred[8][128];           // 4 KB per-pos sumsq partials
        float colrn[128];
    } big;                             // ~36.5 KB
    struct {
        float sv[256];
        int   si[256];
        float tvs[512];
        float red[256];
    } fus;                             // 5 KB
};

__global__ __launch_bounds__(256, 2)   // 256 unified regs/wave: no spill
void k_mega(const float* __restrict__ video, const float* __restrict__ sn,
            const unsigned short* __restrict__ snb,
            const float* __restrict__ iou2d, const float* __restrict__ iou2ds,
            float* __restrict__ iv, float* __restrict__ part) {
    __shared__ SMem sm;
    const int t = threadIdx.x;

    if (blockIdx.x < MM) {
        // ---------------- fused per-target path ----------------
        const int m = blockIdx.x;
        {   // argmax of iou2ds[m] over valid (upper-tri) positions, tie -> lowest pos
            float best = -1e30f; int bi = 1 << 30;
            const float* row = iou2ds + (size_t)m * NSQ;
            for (int pos = t; pos < NSQ; pos += 256) {
                float v = row[pos];
                bool valid = (pos & 63) >= (pos >> 6);
                if (valid && (v > best || (v == best && pos < bi))) { best = v; bi = pos; }
            }
            sm.fus.sv[t] = best; sm.fus.si[t] = bi;
            __syncthreads();
            for (int off = 128; off > 0; off >>= 1) {
                if (t < off) {
                    float v2 = sm.fus.sv[t + off]; int i2 = sm.fus.si[t + off];
                    if (v2 > sm.fus.sv[t] || (v2 == sm.fus.sv[t] && i2 < sm.fus.si[t])) {
                        sm.fus.sv[t] = v2; sm.fus.si[t] = i2;
                    }
                }
                __syncthreads();
            }
        }
        const int flat = sm.fus.si[0];
        const int b = m >> 3;                     // scatter_m2v

        // gather + normalize the top column
        const float* base = video + (size_t)b * CC * NSQ + flat;
        float x0 = base[(size_t)t * NSQ];
        float x1 = base[(size_t)(t + 256) * NSQ];
        sm.fus.red[t] = x0 * x0 + x1 * x1;
        __syncthreads();
        for (int off = 128; off > 0; off >>= 1) {
            if (t < off) sm.fus.red[t] += sm.fus.red[t + off];
            __syncthreads();
        }
        float rn = 1.0f / fmaxf(sqrtf(sm.fus.red[0]), 1e-12f);
        sm.fus.tvs[t] = x0 * rn;
        sm.fus.tvs[t + 256] = x1 * rn;
        __syncthreads();

        // iv row: thread (s = t&127, h = t>>7) computes half-dot
        const int s = t & 127, h = t >> 7;
        const float4* a4 = (const float4*)(sm.fus.tvs + h * 256);
        const float4* b4 = (const float4*)(sn + (size_t)s * CC + h * 256);
        float acc = 0.f;
#pragma unroll 8
        for (int c = 0; c < 64; c++) {
            float4 a = a4[c], bb = b4[c];
            acc += a.x * bb.x + a.y * bb.y + a.z * bb.z + a.w * bb.w;
        }
        __syncthreads();
        sm.fus.red[t] = acc;
        __syncthreads();
        if (t < 128) iv[(size_t)m * SS + t] = sm.fus.red[t] + sm.fus.red[t + 128];
        return;
    }

    // ---------------- big dense MFMA path ----------------
    const int w    = t >> 6;          // wave 0..3
    const int lane = t & 63;
    const int q    = lane >> 4;       // quad 0..3
    const int l15  = lane & 15;
    const int bid  = blockIdx.x - MM; // 0..1023
    const int b    = bid >> 5;        // video
    const int pos0 = (bid & 31) * 128;

    // loader identities
    const int tg = t & 31;            // position group (4 consecutive pos)
    const int cg = t >> 5;            // channel group (8 channels)
    const float* vbase = video + ((size_t)b * CC + cg * 8) * NSQ + pos0 + tg * 4;
    const unsigned short* snbA = snb + (size_t)(t >> 3) * CC + (t & 7) * 8;

    // register prefetch (double-buffered across K-iterations)
    float4 prB[8];
    bf16x8 prA[4];
#pragma unroll
    for (int i = 0; i < 8; i++) prB[i] = *(const float4*)(vbase + (size_t)i * NSQ);
#pragma unroll
    for (int it = 0; it < 4; it++)
        prA[it] = *(const bf16x8*)(snbA + (size_t)it * 32 * CC);

    f32x4 acc[2][8];
#pragma unroll
    for (int i = 0; i < 2; i++)
#pragma unroll
        for (int j = 0; j < 8; j++) acc[i][j] = (f32x4){0.f, 0.f, 0.f, 0.f};

    float sq4[4] = {0.f, 0.f, 0.f, 0.f};

    for (int k0 = 0; k0 < CC; k0 += 64) {
        // ---- write phase (consumes prefetch registers)
#pragma unroll
        for (int it = 0; it < 4; it++) {
            int row = (t >> 3) + it * 32;
            int sw = (((t & 7) ^ (row & 7) ^ ((row >> 3) & 7)) & 7) * 8;
            *(bf16x8*)(sm.big.sA + row * 64 + sw) = prA[it];
        }
#pragma unroll
        for (int p = 0; p < 4; p++) {
            int pos = tg * 4 + p;
            union { float4 v; float f[4]; } u0, u1, u2, u3, u4, u5, u6, u7;
            u0.v = prB[0]; u1.v = prB[1]; u2.v = prB[2]; u3.v = prB[3];
            u4.v = prB[4]; u5.v = prB[5]; u6.v = prB[6]; u7.v = prB[7];
            float v0 = u0.f[p], v1 = u1.f[p], v2 = u2.f[p], v3 = u3.f[p];
            float v4 = u4.f[p], v5 = u5.f[p], v6 = u6.f[p], v7 = u7.f[p];
            sq4[p] += v0 * v0 + v1 * v1 + v2 * v2 + v3 * v3
                    + v4 * v4 + v5 * v5 + v6 * v6 + v7 * v7;
            unsigned uu[4];
            uu[0] = pk2(v0, v1); uu[1] = pk2(v2, v3);
            uu[2] = pk2(v4, v5); uu[3] = pk2(v6, v7);
            int sw = ((cg ^ (pos & 7) ^ ((pos >> 3) & 7)) & 7) * 8;
            *(bf16x8*)(sm.big.vB + pos * 64 + sw) = *(bf16x8*)uu;
        }
        __syncthreads();

        // ---- issue next iteration's global loads (in flight over MFMA phase)
        if (k0 + 64 < CC) {
            const int kn = k0 + 64;
#pragma unroll
            for (int i = 0; i < 8; i++)
                prB[i] = *(const float4*)(vbase + (size_t)(kn + i) * NSQ);
#pragma unroll
            for (int it = 0; it < 4; it++)
                prA[it] = *(const bf16x8*)(snbA + (size_t)it * 32 * CC + kn);
        }

        // ---- compute: two K=32 sub-steps
#pragma unroll
        for (int ks = 0; ks < 64; ks += 32) {
            const int G = (ks >> 3) + q;
            bf16x8 a[2], bfr[8];
#pragma unroll
            for (int rt = 0; rt < 2; rt++) {
                int row = w * 32 + rt * 16 + l15;
                int sw = ((G ^ (row & 7) ^ ((row >> 3) & 7)) & 7) * 8;
                a[rt] = *(const bf16x8*)(sm.big.sA + row * 64 + sw);
            }
#pragma unroll
            for (int ct = 0; ct < 8; ct++) {
                int col = ct * 16 + l15;
                int sw = ((G ^ (col & 7) ^ ((col >> 3) & 7)) & 7) * 8;
                bfr[ct] = *(const bf16x8*)(sm.big.vB + col * 64 + sw);
            }
#pragma unroll
            for (int rt = 0; rt < 2; rt++)
#pragma unroll
                for (int ct = 0; ct < 8; ct++)
                    acc[rt][ct] = __builtin_amdgcn_mfma_f32_16x16x32_bf16(
                        a[rt], bfr[ct], acc[rt][ct], 0, 0, 0);
        }
        __syncthreads();
    }

    // column reciprocal norms
#pragma unroll
    for (int p = 0; p < 4; p++) sm.big.sqred[cg][tg * 4 + p] = sq4[p];
    __syncthreads();
    if (t < 128) {
        float s2 = 0.f;
#pragma unroll
        for (int g = 0; g < 8; g++) s2 += sm.big.sqred[g][t];
        sm.big.colrn[t] = 1.0f / fmaxf(sqrtf(s2), 1e-12f);
    }
    __syncthreads();

    // epilogue: scale, exp, masks (same-video IoU exclusion + lower-tri), reduce
    float crn[8];
#pragma unroll
    for (int ct = 0; ct < 8; ct++) crn[ct] = sm.big.colrn[ct * 16 + l15];
    // D layout: row = w*32 + rt*16 + q*4 + r, col = ct*16 + l15
#pragma unroll
    for (int rt = 0; rt < 2; rt++) {
#pragma unroll
        for (int r = 0; r < 4; r++) {
            int s = w * 32 + rt * 16 + q * 4 + r;
            bool match = ((s >> 2) == b);          // sentence's video == block's video
            float rowsum = 0.f;
#pragma unroll
            for (int ct = 0; ct < 8; ct++) {
                int pos = pos0 + ct * 16 + l15;
                float e = __expf(acc[rt][ct][r] * crn[ct] * 10.0f);   // / T_TEMP
                if (match && iou2d[(size_t)s * NSQ + pos] > 0.5f) e = 0.f;
                if ((pos & 63) < (pos >> 6)) e = 0.f;   // lower-tri: not a proposal
                rowsum += e;
            }
#pragma unroll
            for (int msk = 1; msk < 16; msk <<= 1)
                rowsum += __shfl_xor(rowsum, msk, 64);
            if (l15 == 0) part[(size_t)bid * 128 + s] = rowsum;
        }
    }
}

// ---------------------------------------------------------------------------
// final: reduce per-block partials -> negq, then both losses.
__global__ void k_final(const float* __restrict__ iv, const float* __restrict__ part,
                        float* __restrict__ out) {
    const int t = threadIdx.x;   // 256 = M
    __shared__ float nqs[256];
    __shared__ float rv[256], rq[256];
    {   // negq[s]: thread (s=t&127, h=t>>7) sums half the 1024 block-partials
        const int sl = t & 127, h = t >> 7;
        float nq = 0.f;
        for (int j = h; j < NBIG; j += 2) nq += part[(size_t)j * 128 + sl];
        nqs[t] = nq;
    }
    __syncthreads();
    const float* row = iv + (size_t)t * SS;
    const int ms = t >> 1;       // scatter_m2s
    float pos = row[ms];
    float nv = 0.f;
    for (int s = 0; s < SS; s++) {
        float e = expf(row[s] * 10.0f);
        if (s == ms) e = 0.f;
        nv += e;
    }
    float pe = expf(pos * 10.0f);
    float negq_ms = nqs[ms] + nqs[ms + 128];
    float lv = logf(pe + nv) - pos * 10.0f;
    float lq = logf(pe + negq_ms) - pos * 10.0f;
    rv[t] = lv; rq[t] = lq;
    __syncthreads();
    for (int off = 128; off > 0; off >>= 1) {
        if (t < off) { rv[t] += rv[t + off]; rq[t] += rq[t + off]; }
        __syncthreads();
    }
    if (t == 0) {
        float liv = rv[0] / 256.f, liq = rq[0] / 256.f;
        out[0] = liv + liq;   // total (WEIGHT=1)
        out[1] = liv;
        out[2] = liq;
    }
}

// ---------------------------------------------------------------------------
extern "C" void kernel_launch(void* const* d_in, const int* in_sizes, int n_in,
                              void* d_out, int out_size, void* d_ws, size_t ws_size,
                              hipStream_t stream) {
    const float* video  = (const float*)d_in[0];   // (B,C,N,N)
    const float* sents  = (const float*)d_in[1];   // (S,C)
    const float* iou2d  = (const float*)d_in[4];   // (S,N,N)
    const float* iou2ds = (const float*)d_in[5];   // (M,N,N)
    float* out = (float*)d_out;

    char* ws = (char*)d_ws;
    float*          sn   = (float*)(ws + WS_SN);
    unsigned short* snb  = (unsigned short*)(ws + WS_SNB);
    float*          iv   = (float*)(ws + WS_IV);
    float*          part = (float*)(ws + WS_PART);

    k_prep <<<128, 256, 0, stream>>>(sents, sn, snb);
    k_mega <<<MM + NBIG, 256, 0, stream>>>(video, sn, snb, iou2d, iou2ds, iv, part);
    k_final<<<1, 256, 0, stream>>>(iv, part, out);
}